// Round 9
// baseline (432.406 us; speedup 1.0000x reference)
//
#include <hip/hip_runtime.h>
#include <cstdint>

typedef __bf16 bf16;
typedef __attribute__((ext_vector_type(8))) __bf16 bf16x8;
typedef __attribute__((ext_vector_type(4))) __bf16 bf16x4;
typedef __attribute__((ext_vector_type(4))) float f32x4;

static __device__ __forceinline__ f32x4 mfma16(bf16x8 a, bf16x8 b, f32x4 c) {
    return __builtin_amdgcn_mfma_f32_16x16x32_bf16(a, b, c, 0, 0, 0);
}
static __device__ __forceinline__ bf16x4 cvt4(f32x4 v) {
    bf16x4 r; r[0]=(bf16)v[0]; r[1]=(bf16)v[1]; r[2]=(bf16)v[2]; r[3]=(bf16)v[3]; return r;
}

// ---------------------------------------------------------------------------
// K1: proj_in.  z_tok[(b,h,w)][o] = sum_c x[b,c,h,w] * Wi[o,c]   (bf16 out)
// Bs pitch 78: transposed-stage scalar writes drop from 8-way to 4-way conflict.
// ---------------------------------------------------------------------------
__global__ __launch_bounds__(256) void k_proj_in(
    const float* __restrict__ x, const float* __restrict__ Wi, bf16* __restrict__ z)
{
    __shared__ bf16 As[128][72];
    __shared__ bf16 Bs[64][78];
    const int tid = threadIdx.x;
    const int lane = tid & 63, w = tid >> 6;
    const int ll = lane & 15, lg = lane >> 4;
    const int b = blockIdx.x >> 9;
    const int n0 = (blockIdx.x & 511) * 64;
    const float* xb = x + (size_t)b * 512 * 32768;

    f32x4 acc[2][4];
    const f32x4 Z4 = {0.f,0.f,0.f,0.f};
    #pragma unroll
    for (int i=0;i<2;i++) { acc[i][0]=Z4; acc[i][1]=Z4; acc[i][2]=Z4; acc[i][3]=Z4; }

    for (int c0 = 0; c0 < 512; c0 += 64) {
        #pragma unroll
        for (int r = 0; r < 8; ++r) {
            int idx = r*256 + tid;
            int o = idx >> 4, cq = idx & 15;
            f32x4 v = *(const f32x4*)(Wi + (size_t)o*512 + c0 + cq*4);
            *(bf16x4*)&As[o][cq*4] = cvt4(v);
        }
        #pragma unroll
        for (int r = 0; r < 4; ++r) {
            int idx = r*256 + tid;
            int k = idx >> 4, nq = idx & 15;
            f32x4 v = *(const f32x4*)(xb + (size_t)(c0 + k)*32768 + n0 + nq*4);
            #pragma unroll
            for (int j=0;j<4;j++) Bs[nq*4+j][k] = (bf16)v[j];
        }
        __syncthreads();
        #pragma unroll
        for (int ks = 0; ks < 2; ++ks) {
            bf16x8 af[2], bfr[4];
            #pragma unroll
            for (int mt=0;mt<2;mt++) af[mt]  = *(const bf16x8*)&As[w*32+mt*16+ll][ks*32+lg*8];
            #pragma unroll
            for (int nt=0;nt<4;nt++) bfr[nt] = *(const bf16x8*)&Bs[nt*16+ll][ks*32+lg*8];
            #pragma unroll
            for (int mt=0;mt<2;mt++)
                #pragma unroll
                for (int nt=0;nt<4;nt++)
                    acc[mt][nt] = mfma16(af[mt], bfr[nt], acc[mt][nt]);
        }
        __syncthreads();
    }
    #pragma unroll
    for (int mt=0;mt<2;mt++)
      #pragma unroll
      for (int nt=0;nt<4;nt++) {
        int o0 = w*32 + mt*16 + lg*4;
        int token = b*32768 + n0 + nt*16 + ll;
        *(bf16x4*)&z[(size_t)token*128 + o0] = cvt4(acc[mt][nt]);
      }
}

// ---------------------------------------------------------------------------
// K2: fused LayerNorm + QKV projection.
// NEW: wave-private W staging (each wave stages only its own 32-row slice of
// wsm, which is all it ever reads) -> single barrier per block (xs), phases
// decoupled across waves. xa fragments hoisted once, reused for Q/K/V.
// ---------------------------------------------------------------------------
__global__ __launch_bounds__(256) void k_qkv(
    const bf16* __restrict__ zin, const float* __restrict__ lnw, const float* __restrict__ lnb,
    const float* __restrict__ Wq, const float* __restrict__ Wk, const float* __restrict__ Wv,
    bf16* __restrict__ Qb, bf16* __restrict__ Kb, bf16* __restrict__ Vt, int nshift)
{
    __shared__ bf16 xs[64][136];
    __shared__ bf16 wsm[128][136];
    const int tid = threadIdx.x;
    const int lane = tid & 63, w = tid >> 6;
    const int ll = lane & 15, lg = lane >> 4;
    const int t0 = blockIdx.x * 64;
    const int N = 1 << nshift;

    {
        const int sub = tid & 15;
        float wv[8], bv[8];
        #pragma unroll
        for (int j=0;j<8;j++){ wv[j]=lnw[sub*8+j]; bv[j]=lnb[sub*8+j]; }
        #pragma unroll
        for (int r=0;r<4;r++){
            int tl = r*16 + (tid >> 4);
            bf16x8 v = *(const bf16x8*)&zin[(size_t)(t0+tl)*128 + sub*8];
            float f[8]; float sm=0.f, ssq=0.f;
            #pragma unroll
            for (int j=0;j<8;j++){ f[j]=(float)v[j]; sm+=f[j]; ssq+=f[j]*f[j]; }
            #pragma unroll
            for (int d=1; d<16; d<<=1){ sm += __shfl_xor(sm,d); ssq += __shfl_xor(ssq,d); }
            float mean = sm*(1.f/128.f);
            float var  = ssq*(1.f/128.f) - mean*mean;
            float rr = rsqrtf(var + 1e-5f);
            bf16x8 ov;
            #pragma unroll
            for (int j=0;j<8;j++) ov[j] = (bf16)((f[j]-mean)*rr*wv[j] + bv[j]);
            *(bf16x8*)&xs[tl][sub*8] = ov;
        }
    }
    __syncthreads();   // the only barrier: xs ready for all waves

    // hoist x fragments (reused across all 3 phases)
    bf16x8 xa[4][4];   // [ks][tt]
    #pragma unroll
    for (int ks=0; ks<4; ++ks)
        #pragma unroll
        for (int tt=0;tt<4;tt++) xa[ks][tt] = *(const bf16x8*)&xs[tt*16+ll][ks*32+lg*8];

    const float* Wm[3] = {Wq, Wk, Wv};
    const f32x4 Z4 = {0.f,0.f,0.f,0.f};
    for (int m = 0; m < 3; ++m) {
        const float scale = (m == 0) ? 0.25503486f : 1.0f;  // log2(e)/sqrt(32)
        // wave-private stage of rows [w*32, w*32+32)
        #pragma unroll
        for (int r=0;r<16;r++){
            int idx = r*64 + lane;
            int o = idx >> 5, q = idx & 31;
            f32x4 v = *(const f32x4*)(Wm[m] + (size_t)(w*32+o)*128 + q*4);
            v[0]*=scale; v[1]*=scale; v[2]*=scale; v[3]*=scale;
            *(bf16x4*)&wsm[w*32+o][q*4] = cvt4(v);
        }
        f32x4 acc[4][2];
        #pragma unroll
        for (int i=0;i<4;i++){ acc[i][0]=Z4; acc[i][1]=Z4; }
        #pragma unroll
        for (int ks=0; ks<4; ++ks){
            bf16x8 wb[2];
            #pragma unroll
            for (int ot=0;ot<2;ot++) wb[ot] = *(const bf16x8*)&wsm[w*32+ot*16+ll][ks*32+lg*8];
            if (m < 2) {
                #pragma unroll
                for (int tt=0;tt<4;tt++)
                    #pragma unroll
                    for (int ot=0;ot<2;ot++)
                        acc[tt][ot] = mfma16(xa[ks][tt], wb[ot], acc[tt][ot]);   // D[token][o]
            } else {
                #pragma unroll
                for (int tt=0;tt<4;tt++)
                    #pragma unroll
                    for (int ot=0;ot<2;ot++)
                        acc[tt][ot] = mfma16(wb[ot], xa[ks][tt], acc[tt][ot]);   // D[o][token]
            }
        }
        if (m < 2) {
            bf16* dst = (m==0) ? Qb : Kb;
            #pragma unroll
            for (int tt=0;tt<4;tt++)
              #pragma unroll
              for (int ot=0;ot<2;ot++)
                #pragma unroll
                for (int r=0;r<4;r++){
                    int token = t0 + tt*16 + lg*4 + r;
                    int sq = token >> nshift, n = token & (N-1);
                    int dk = ot*16 + ll;
                    dst[((size_t)(sq*4 + w)*N + n)*32 + dk] = (bf16)acc[tt][ot][r];
                }
        } else {
            #pragma unroll
            for (int tt=0;tt<4;tt++)
              #pragma unroll
              for (int ot=0;ot<2;ot++)
                #pragma unroll
                for (int r=0;r<4;r++){
                    int dk = ot*16 + lg*4 + r;
                    int token = t0 + tt*16 + ll;
                    int sq = token >> nshift, n = token & (N-1);
                    Vt[((size_t)(sq*4 + w)*32 + dk)*N + n] = (bf16)acc[tt][ot][r];
                }
        }
    }
}

// ---------------------------------------------------------------------------
// K3: attention (r6 verbatim — verified).
// ---------------------------------------------------------------------------
template<int N>
__global__ __launch_bounds__(256, 2) void k_attn(
    const bf16* __restrict__ Qb, const bf16* __restrict__ Kb, const bf16* __restrict__ Vt,
    const bf16* __restrict__ tin, bf16* __restrict__ tout, int spb_shift)
{
    constexpr int T = N/16;
    constexpr int NQT = N/64;
    constexpr int VP = N + 8;
    __shared__ bf16 Ks[N][40];
    __shared__ bf16 Vs[32][VP];
    const int tid = threadIdx.x;
    const int lane = tid & 63, w = tid >> 6;
    const int ll = lane & 15, lg = lane >> 4;
    const int sh = blockIdx.x;
    const int s = sh >> 2, h = sh & 3;
    const size_t base = (size_t)sh * N * 32;

    #pragma unroll
    for (int r=0;r<N/64;r++){
        int idx = r*256 + tid;
        int n = idx >> 2, c = idx & 3;
        *(bf16x8*)&Ks[n][c*8] = *(const bf16x8*)&Kb[base + (size_t)n*32 + c*8];
    }
    #pragma unroll
    for (int r=0;r<N/64;r++){
        int idx = r*256 + tid;
        int dd = idx / (N/8), nc = idx % (N/8);
        *(bf16x8*)&Vs[dd][nc*8] = *(const bf16x8*)&Vt[base + (size_t)dd*N + nc*8];
    }
    bf16x8 qf[NQT];
    #pragma unroll
    for (int qt=0;qt<NQT;qt++)
        qf[qt] = *(const bf16x8*)&Qb[base + (size_t)(w*(N/4) + qt*16 + ll)*32 + lg*8];
    __syncthreads();

    const f32x4 Z4 = {0.f,0.f,0.f,0.f};
    f32x4 Oacc[NQT][2];
    float smv[NQT];

    #pragma unroll
    for (int qt=0; qt<NQT; ++qt){
        f32x4 sc[T];
        #pragma unroll
        for (int t=0;t<T;t++){
            bf16x8 kf = *(const bf16x8*)&Ks[t*16+ll][lg*8];
            sc[t] = mfma16(kf, qf[qt], Z4);   // D[col=q=ll][row=key=t*16+lg*4+r]
        }
        float mx = sc[0][0];
        #pragma unroll
        for (int t=0;t<T;t++)
            #pragma unroll
            for (int r=0;r<4;r++) mx = fmaxf(mx, sc[t][r]);
        mx = fmaxf(mx, __shfl_xor(mx, 16));
        mx = fmaxf(mx, __shfl_xor(mx, 32));
        float sm = 0.f;
        #pragma unroll
        for (int t=0;t<T;t++){
            #pragma unroll
            for (int r=0;r<4;r++){ float p = exp2f(sc[t][r] - mx); sc[t][r] = p; sm += p; }
        }
        sm += __shfl_xor(sm, 16);
        sm += __shfl_xor(sm, 32);
        smv[qt] = sm;

        f32x4 O0 = Z4, O1 = Z4;
        #pragma unroll
        for (int ks=0; ks<N/32; ++ks){
            bf16x4 pa = cvt4(sc[2*ks]), pb = cvt4(sc[2*ks+1]);
            bf16x8 pf;
            #pragma unroll
            for (int j=0;j<4;j++){ pf[j] = pa[j]; pf[4+j] = pb[j]; }
            bf16x4 a0 = *(const bf16x4*)&Vs[ll][ks*32 + lg*4];
            bf16x4 a1 = *(const bf16x4*)&Vs[ll][ks*32 + lg*4 + 16];
            bf16x4 b0 = *(const bf16x4*)&Vs[16+ll][ks*32 + lg*4];
            bf16x4 b1 = *(const bf16x4*)&Vs[16+ll][ks*32 + lg*4 + 16];
            bf16x8 v0, v1;
            #pragma unroll
            for (int j=0;j<4;j++){ v0[j]=a0[j]; v0[4+j]=a1[j]; v1[j]=b0[j]; v1[4+j]=b1[j]; }
            O0 = mfma16(v0, pf, O0);   // D[col=q=ll][row=dout=lg*4+r]
            O1 = mfma16(v1, pf, O1);
        }
        Oacc[qt][0] = O0; Oacc[qt][1] = O1;
    }

    __syncthreads();   // Ks/Vs dead; reuse Ks as O staging
    #pragma unroll
    for (int qt=0; qt<NQT; ++qt){
        float inv = 1.f / smv[qt];
        int q = w*(N/4) + qt*16 + ll;
        #pragma unroll
        for (int dt=0; dt<2; ++dt){
            bf16x4 o4;
            #pragma unroll
            for (int r=0;r<4;r++) o4[r] = (bf16)(Oacc[qt][dt][r]*inv);
            *(bf16x4*)&Ks[q][dt*16 + lg*4] = o4;
        }
    }
    __syncthreads();
    const int spb_mask = (1 << spb_shift) - 1;
    #pragma unroll
    for (int it=0; it<N/64; ++it){
        int q = it*64 + (tid >> 2);
        int part = tid & 3;
        size_t ti = ((size_t)(s*N + q))*128 + h*32 + part*8;
        size_t to = ((size_t)((((s >> spb_shift)*N + q) << spb_shift) + (s & spb_mask)))*128 + h*32 + part*8;
        bf16x8 a = *(const bf16x8*)&Ks[q][part*8];
        bf16x8 rs = *(const bf16x8*)&tin[ti];
        bf16x8 o;
        #pragma unroll
        for (int j=0;j<8;j++) o[j] = (bf16)((float)a[j] + (float)rs[j]);
        *(bf16x8*)&tout[to] = o;
    }
}

// ---------------------------------------------------------------------------
// K4a: Gram matrix M_b = f^T [f | 1], now 512 slices (256 tokens) -> 2 blk/CU.
// ---------------------------------------------------------------------------
__global__ __launch_bounds__(256) void k_cov(
    const bf16* __restrict__ f, float* __restrict__ part)
{
    __shared__ bf16 ct[144][72];   // rows 0..127 channels, 128 ones, 129..143 zero
    const int tid = threadIdx.x;
    const int lane = tid & 63, w = tid >> 6;
    const int ll = lane & 15, lg = lane >> 4;
    const int b = blockIdx.x >> 7, sl = blockIdx.x & 127;
    const size_t tb = (size_t)b*32768 + (size_t)sl*256;

    for (int idx = tid; idx < 16*72; idx += 256)
        ct[128 + idx/72][idx%72] = (bf16)((idx/72 == 0) ? 1.0f : 0.0f);

    const f32x4 Z4 = {0.f,0.f,0.f,0.f};
    f32x4 acc[2][9];
    #pragma unroll
    for (int mt=0;mt<2;mt++)
        #pragma unroll
        for (int jt=0;jt<9;jt++) acc[mt][jt] = Z4;

    for (int c = 0; c < 4; ++c){
        __syncthreads();
        #pragma unroll
        for (int it=0; it<4; ++it){
            int cg = it*4 + w;      // channel group (8 ch)
            bf16x8 v = *(const bf16x8*)&f[(tb + c*64 + lane)*128 + cg*8];
            #pragma unroll
            for (int j=0;j<8;j++) ct[cg*8+j][lane] = v[j];
        }
        __syncthreads();
        #pragma unroll
        for (int ks=0; ks<2; ++ks){
            bf16x8 am[2], bm[9];
            #pragma unroll
            for (int mt=0;mt<2;mt++) am[mt] = *(const bf16x8*)&ct[w*32+mt*16+ll][ks*32+lg*8];
            #pragma unroll
            for (int jt=0;jt<9;jt++) bm[jt] = *(const bf16x8*)&ct[jt*16+ll][ks*32+lg*8];
            #pragma unroll
            for (int mt=0;mt<2;mt++)
                #pragma unroll
                for (int jt=0;jt<9;jt++)
                    acc[mt][jt] = mfma16(am[mt], bm[jt], acc[mt][jt]);  // D[col=j][row=i]
        }
    }
    float* pp = part + (size_t)blockIdx.x * 18432;   // [128][144]
    #pragma unroll
    for (int mt=0;mt<2;mt++)
        #pragma unroll
        for (int jt=0;jt<9;jt++)
            #pragma unroll
            for (int r=0;r<4;r++){
                int i = w*32 + mt*16 + lg*4 + r;
                int j = jt*16 + ll;
                pp[i*144 + j] = acc[mt][jt][r];
            }
}

// K4b: reduce slice partials -> Mred[b][128][144]
__global__ __launch_bounds__(256) void k_redM(
    const float* __restrict__ part, float* __restrict__ Mred)
{
    const int b = blockIdx.x / 72, r = blockIdx.x % 72;
    const int e = r*256 + threadIdx.x;
    float s = 0.f;
    for (int sl = 0; sl < 128; ++sl)
        s += part[((size_t)(b*128 + sl))*18432 + e];
    Mred[(size_t)b*18432 + e] = s;
}

// K4c: per-(b,group) stats via quadratic forms w_o^T M w_o (fp32 W).
__global__ __launch_bounds__(256) void k_gnstat2(
    const float* __restrict__ Mred, const float* __restrict__ Wo, float* __restrict__ stats)
{
    __shared__ float Ms[18432];        // [i][j] pitch 144
    __shared__ float wv[16][132];
    __shared__ float redq[16], redm[16];
    const int tid = threadIdx.x;
    const int b = blockIdx.x >> 5, g = blockIdx.x & 31;
    #pragma unroll 4
    for (int r=0;r<72;r++){ int off = r*256+tid; Ms[off] = Mred[(size_t)b*18432 + off]; }
    for (int idx=tid; idx<2048; idx+=256){
        int o = idx>>7, i = idx&127;
        wv[o][i] = Wo[(size_t)(g*16+o)*128 + i];
    }
    __syncthreads();
    const int o = tid >> 4, ts = tid & 15;
    float q = 0.f, mn = 0.f;
    for (int ii=0; ii<8; ++ii){
        int i = ts*8 + ii;
        const float wi = wv[o][i];
        float dot = 0.f;
        for (int jj=0; jj<128; ++jj){
            int j = (jj + ts*8) & 127;   // stagger to spread LDS banks
            dot += Ms[i*144 + j] * wv[o][j];
        }
        q  += wi*dot;
        mn += wi*Ms[i*144 + 128];        // colsum column
    }
    #pragma unroll
    for (int d=1; d<16; d<<=1){ q += __shfl_xor(q,d); mn += __shfl_xor(mn,d); }
    if (ts == 0){ redq[o] = q; redm[o] = mn; }
    __syncthreads();
    if (tid == 0){
        float sq=0.f, smm=0.f;
        for (int o2=0;o2<16;o2++){ sq += redq[o2]; smm += redm[o2]; }
        float mean = smm * (1.f/524288.f);
        float var  = sq  * (1.f/524288.f) - mean*mean;
        stats[(b*32+g)*2]   = mean;
        stats[(b*32+g)*2+1] = rsqrtf(var + 1e-5f);
    }
}

// ---------------------------------------------------------------------------
// K5: proj_out GEMM + GroupNorm apply + residual + fp32 store (r6 verbatim).
// ---------------------------------------------------------------------------
__global__ __launch_bounds__(256) void k_apply(
    const bf16* __restrict__ f, const float* __restrict__ Wo, const float* __restrict__ x,
    const float* __restrict__ stats, const float* __restrict__ gw, const float* __restrict__ gb,
    float* __restrict__ out)
{
    __shared__ bf16 As[128][136];   // W tile during GEMM; fp32 O tile after
    __shared__ bf16 Bs[64][136];
    const int tid = threadIdx.x;
    const int lane = tid & 63, w = tid >> 6;
    const int ll = lane & 15, lg = lane >> 4;
    const int b  = blockIdx.x >> 11;
    const int ms = (blockIdx.x >> 9) & 3;
    const int ns = blockIdx.x & 511;
    const int n0 = ns*64, o0 = ms*128;

    #pragma unroll
    for (int r=0;r<16;r++){
        int idx = r*256 + tid;
        int o = idx >> 5, q = idx & 31;
        f32x4 v = *(const f32x4*)(Wo + (size_t)(o0+o)*128 + q*4);
        *(bf16x4*)&As[o][q*4] = cvt4(v);
    }
    #pragma unroll
    for (int r=0;r<4;r++){
        int idx = r*256 + tid;
        int nl = idx >> 4, ch = idx & 15;
        *(bf16x8*)&Bs[nl][ch*8] = *(const bf16x8*)&f[(size_t)(b*32768 + n0 + nl)*128 + ch*8];
    }
    __syncthreads();
    const f32x4 Z4 = {0.f,0.f,0.f,0.f};
    f32x4 acc[2][4];
    #pragma unroll
    for (int i=0;i<2;i++){ acc[i][0]=Z4; acc[i][1]=Z4; acc[i][2]=Z4; acc[i][3]=Z4; }
    #pragma unroll
    for (int ks=0;ks<4;ks++){
        bf16x8 af[2], bfr[4];
        #pragma unroll
        for (int mt=0;mt<2;mt++) af[mt]  = *(const bf16x8*)&As[w*32+mt*16+ll][ks*32+lg*8];
        #pragma unroll
        for (int nt=0;nt<4;nt++) bfr[nt] = *(const bf16x8*)&Bs[nt*16+ll][ks*32+lg*8];
        #pragma unroll
        for (int mt=0;mt<2;mt++)
            #pragma unroll
            for (int nt=0;nt<4;nt++)
                acc[mt][nt] = mfma16(af[mt], bfr[nt], acc[mt][nt]);
    }
    __syncthreads();                    // As reads done; reuse as fp32 [128][68]
    float* Od = (float*)&As[0][0];
    #pragma unroll
    for (int mt=0;mt<2;mt++){
        int g = ms*8 + w*2 + mt;
        float mean = stats[(b*32+g)*2];
        float rstd = stats[(b*32+g)*2+1];
        #pragma unroll
        for (int r=0;r<4;r++){
            int o_l = w*32 + mt*16 + lg*4 + r;
            float sw = rstd * gw[o0 + o_l];
            float sb = gb[o0 + o_l] - mean*sw;
            #pragma unroll
            for (int nt=0;nt<4;nt++)
                Od[o_l*68 + nt*16 + ll] = acc[mt][nt][r]*sw + sb;
        }
    }
    __syncthreads();
    #pragma unroll
    for (int it=0; it<8; ++it){
        int idx = it*256 + tid;
        int o_l = idx >> 4, c4 = (idx & 15)*4;
        size_t gi = (size_t)(b*512 + o0 + o_l)*32768 + n0 + c4;
        f32x4 xv = *(const f32x4*)(x + gi);
        f32x4 ov = *(const f32x4*)(Od + o_l*68 + c4);
        f32x4 res;
        #pragma unroll
        for (int j=0;j<4;j++) res[j] = xv[j] + ov[j];
        *(f32x4*)(out + gi) = res;
    }
}

// ---------------------------------------------------------------------------
extern "C" void kernel_launch(void* const* d_in, const int* in_sizes, int n_in,
                              void* d_out, int out_size, void* d_ws, size_t ws_size,
                              hipStream_t stream)
{
    (void)in_sizes; (void)n_in; (void)out_size; (void)ws_size;
    const float* x   = (const float*)d_in[0];
    const float* wi  = (const float*)d_in[1];
    const float* tq  = (const float*)d_in[2];
    const float* tk  = (const float*)d_in[3];
    const float* tv  = (const float*)d_in[4];
    const float* tnw = (const float*)d_in[5];
    const float* tnb = (const float*)d_in[6];
    const float* fq  = (const float*)d_in[7];
    const float* fk  = (const float*)d_in[8];
    const float* fv  = (const float*)d_in[9];
    const float* fnw = (const float*)d_in[10];
    const float* fnb = (const float*)d_in[11];
    const float* wo  = (const float*)d_in[12];
    const float* gnw = (const float*)d_in[13];
    const float* gnb = (const float*)d_in[14];
    float* out = (float*)d_out;

    char* ws = (char*)d_ws;
    const size_t MB = (size_t)1 << 20;
    bf16* Z    = (bf16*)(ws);             // 32MB tokens (b,h,w), reused as f_out
    bf16* QB   = (bf16*)(ws + 32*MB);     // 32MB
    bf16* KB   = (bf16*)(ws + 64*MB);     // 32MB
    bf16* VT   = (bf16*)(ws + 96*MB);     // 32MB (transposed V)
    bf16* TOUT = (bf16*)(ws + 128*MB);    // 32MB tokens (b,w,h)
    float* PARTC = (float*)(ws + 32*MB);  // 37.75MB (QB/KB dead by then)
    float* MRED  = (float*)(ws + 112*MB); // 294KB  (VT dead by then)
    float* STATS = (float*)(ws + 120*MB);

    k_proj_in<<<2048, 256, 0, stream>>>(x, wi, Z);
    k_qkv<<<2048, 256, 0, stream>>>(Z, tnw, tnb, tq, tk, tv, QB, KB, VT, 8);
    k_attn<256><<<2048, 256, 0, stream>>>(QB, KB, VT, Z, TOUT, 7);
    k_qkv<<<2048, 256, 0, stream>>>(TOUT, fnw, fnb, fq, fk, fv, QB, KB, VT, 7);
    k_attn<128><<<4096, 256, 0, stream>>>(QB, KB, VT, TOUT, Z, 8);
    k_cov<<<512, 256, 0, stream>>>(Z, PARTC);
    k_redM<<<288, 256, 0, stream>>>(PARTC, MRED);
    k_gnstat2<<<128, 256, 0, stream>>>(MRED, wo, STATS);
    k_apply<<<8192, 256, 0, stream>>>(Z, wo, x, STATS, gnw, gnb, out);
}

// Round 10
// 398.004 us; speedup vs baseline: 1.0864x; 1.0864x over previous
//
#include <hip/hip_runtime.h>
#include <cstdint>

typedef __bf16 bf16;
typedef __attribute__((ext_vector_type(8))) __bf16 bf16x8;
typedef __attribute__((ext_vector_type(4))) __bf16 bf16x4;
typedef __attribute__((ext_vector_type(4))) float f32x4;

static __device__ __forceinline__ f32x4 mfma16(bf16x8 a, bf16x8 b, f32x4 c) {
    return __builtin_amdgcn_mfma_f32_16x16x32_bf16(a, b, c, 0, 0, 0);
}
static __device__ __forceinline__ bf16x4 cvt4(f32x4 v) {
    bf16x4 r; r[0]=(bf16)v[0]; r[1]=(bf16)v[1]; r[2]=(bf16)v[2]; r[3]=(bf16)v[3]; return r;
}

// ---------------------------------------------------------------------------
// K1: proj_in.  z_tok[(b,h,w)][o] = sum_c x[b,c,h,w] * Wi[o,c]   (bf16 out)
// r6 + Bs pitch 78 (row step 156B == 28 dw mod 32 -> 4-way instead of 8-way
// conflict on the transposed scalar ds_write_b16 staging).
// ---------------------------------------------------------------------------
__global__ __launch_bounds__(256) void k_proj_in(
    const float* __restrict__ x, const float* __restrict__ Wi, bf16* __restrict__ z)
{
    __shared__ bf16 As[128][72];
    __shared__ bf16 Bs[64][78];
    const int tid = threadIdx.x;
    const int lane = tid & 63, w = tid >> 6;
    const int ll = lane & 15, lg = lane >> 4;
    const int b = blockIdx.x >> 9;
    const int n0 = (blockIdx.x & 511) * 64;
    const float* xb = x + (size_t)b * 512 * 32768;

    f32x4 acc[2][4];
    const f32x4 Z4 = {0.f,0.f,0.f,0.f};
    #pragma unroll
    for (int i=0;i<2;i++) { acc[i][0]=Z4; acc[i][1]=Z4; acc[i][2]=Z4; acc[i][3]=Z4; }

    for (int c0 = 0; c0 < 512; c0 += 64) {
        #pragma unroll
        for (int r = 0; r < 8; ++r) {
            int idx = r*256 + tid;
            int o = idx >> 4, cq = idx & 15;
            f32x4 v = *(const f32x4*)(Wi + (size_t)o*512 + c0 + cq*4);
            *(bf16x4*)&As[o][cq*4] = cvt4(v);
        }
        #pragma unroll
        for (int r = 0; r < 4; ++r) {
            int idx = r*256 + tid;
            int k = idx >> 4, nq = idx & 15;
            f32x4 v = *(const f32x4*)(xb + (size_t)(c0 + k)*32768 + n0 + nq*4);
            #pragma unroll
            for (int j=0;j<4;j++) Bs[nq*4+j][k] = (bf16)v[j];
        }
        __syncthreads();
        #pragma unroll
        for (int ks = 0; ks < 2; ++ks) {
            bf16x8 af[2], bfr[4];
            #pragma unroll
            for (int mt=0;mt<2;mt++) af[mt]  = *(const bf16x8*)&As[w*32+mt*16+ll][ks*32+lg*8];
            #pragma unroll
            for (int nt=0;nt<4;nt++) bfr[nt] = *(const bf16x8*)&Bs[nt*16+ll][ks*32+lg*8];
            #pragma unroll
            for (int mt=0;mt<2;mt++)
                #pragma unroll
                for (int nt=0;nt<4;nt++)
                    acc[mt][nt] = mfma16(af[mt], bfr[nt], acc[mt][nt]);
        }
        __syncthreads();
    }
    #pragma unroll
    for (int mt=0;mt<2;mt++)
      #pragma unroll
      for (int nt=0;nt<4;nt++) {
        int o0 = w*32 + mt*16 + lg*4;
        int token = b*32768 + n0 + nt*16 + ll;
        *(bf16x4*)&z[(size_t)token*128 + o0] = cvt4(acc[mt][nt]);
      }
}

// ---------------------------------------------------------------------------
// K2: fused LayerNorm + QKV projection. r6 structure (cooperative W staging,
// same barrier count) + xa fragments hoisted once after the LN barrier
// (xs never rewritten): 48 -> 16 ds_read_b128 per wave.
// ---------------------------------------------------------------------------
__global__ __launch_bounds__(256) void k_qkv(
    const bf16* __restrict__ zin, const float* __restrict__ lnw, const float* __restrict__ lnb,
    const float* __restrict__ Wq, const float* __restrict__ Wk, const float* __restrict__ Wv,
    bf16* __restrict__ Qb, bf16* __restrict__ Kb, bf16* __restrict__ Vt, int nshift)
{
    __shared__ bf16 xs[64][136];
    __shared__ bf16 wsm[128][136];
    const int tid = threadIdx.x;
    const int lane = tid & 63, w = tid >> 6;
    const int ll = lane & 15, lg = lane >> 4;
    const int t0 = blockIdx.x * 64;
    const int N = 1 << nshift;

    {
        const int sub = tid & 15;
        float wv[8], bv[8];
        #pragma unroll
        for (int j=0;j<8;j++){ wv[j]=lnw[sub*8+j]; bv[j]=lnb[sub*8+j]; }
        #pragma unroll
        for (int r=0;r<4;r++){
            int tl = r*16 + (tid >> 4);
            bf16x8 v = *(const bf16x8*)&zin[(size_t)(t0+tl)*128 + sub*8];
            float f[8]; float sm=0.f, ssq=0.f;
            #pragma unroll
            for (int j=0;j<8;j++){ f[j]=(float)v[j]; sm+=f[j]; ssq+=f[j]*f[j]; }
            #pragma unroll
            for (int d=1; d<16; d<<=1){ sm += __shfl_xor(sm,d); ssq += __shfl_xor(ssq,d); }
            float mean = sm*(1.f/128.f);
            float var  = ssq*(1.f/128.f) - mean*mean;
            float rr = rsqrtf(var + 1e-5f);
            bf16x8 ov;
            #pragma unroll
            for (int j=0;j<8;j++) ov[j] = (bf16)((f[j]-mean)*rr*wv[j] + bv[j]);
            *(bf16x8*)&xs[tl][sub*8] = ov;
        }
    }
    __syncthreads();   // xs ready for all waves

    // hoist x fragments once (xs is never rewritten)
    bf16x8 xa[4][4];   // [ks][tt]
    #pragma unroll
    for (int ks=0; ks<4; ++ks)
        #pragma unroll
        for (int tt=0;tt<4;tt++) xa[ks][tt] = *(const bf16x8*)&xs[tt*16+ll][ks*32+lg*8];

    const float* Wm[3] = {Wq, Wk, Wv};
    const f32x4 Z4 = {0.f,0.f,0.f,0.f};
    for (int m = 0; m < 3; ++m) {
        if (m > 0) __syncthreads();   // previous phase's wsm readers done
        const float scale = (m == 0) ? 0.25503486f : 1.0f;  // log2(e)/sqrt(32)
        #pragma unroll
        for (int r=0;r<16;r++){
            int idx = r*256 + tid;
            int o = idx >> 5, q = idx & 31;
            f32x4 v = *(const f32x4*)(Wm[m] + (size_t)o*128 + q*4);
            v[0]*=scale; v[1]*=scale; v[2]*=scale; v[3]*=scale;
            *(bf16x4*)&wsm[o][q*4] = cvt4(v);
        }
        __syncthreads();
        f32x4 acc[4][2];
        #pragma unroll
        for (int i=0;i<4;i++){ acc[i][0]=Z4; acc[i][1]=Z4; }
        #pragma unroll
        for (int ks=0; ks<4; ++ks){
            bf16x8 wb[2];
            #pragma unroll
            for (int ot=0;ot<2;ot++) wb[ot] = *(const bf16x8*)&wsm[w*32+ot*16+ll][ks*32+lg*8];
            if (m < 2) {
                #pragma unroll
                for (int tt=0;tt<4;tt++)
                    #pragma unroll
                    for (int ot=0;ot<2;ot++)
                        acc[tt][ot] = mfma16(xa[ks][tt], wb[ot], acc[tt][ot]);   // D[token][o]
            } else {
                #pragma unroll
                for (int tt=0;tt<4;tt++)
                    #pragma unroll
                    for (int ot=0;ot<2;ot++)
                        acc[tt][ot] = mfma16(wb[ot], xa[ks][tt], acc[tt][ot]);   // D[o][token]
            }
        }
        if (m < 2) {
            bf16* dst = (m==0) ? Qb : Kb;
            #pragma unroll
            for (int tt=0;tt<4;tt++)
              #pragma unroll
              for (int ot=0;ot<2;ot++)
                #pragma unroll
                for (int r=0;r<4;r++){
                    int token = t0 + tt*16 + lg*4 + r;
                    int sq = token >> nshift, n = token & (N-1);
                    int dk = ot*16 + ll;
                    dst[((size_t)(sq*4 + w)*N + n)*32 + dk] = (bf16)acc[tt][ot][r];
                }
        } else {
            #pragma unroll
            for (int tt=0;tt<4;tt++)
              #pragma unroll
              for (int ot=0;ot<2;ot++)
                #pragma unroll
                for (int r=0;r<4;r++){
                    int dk = ot*16 + lg*4 + r;
                    int token = t0 + tt*16 + ll;
                    int sq = token >> nshift, n = token & (N-1);
                    Vt[((size_t)(sq*4 + w)*32 + dk)*N + n] = (bf16)acc[tt][ot][r];
                }
        }
    }
}

// ---------------------------------------------------------------------------
// K3: attention (r6 verbatim — verified).
// ---------------------------------------------------------------------------
template<int N>
__global__ __launch_bounds__(256, 2) void k_attn(
    const bf16* __restrict__ Qb, const bf16* __restrict__ Kb, const bf16* __restrict__ Vt,
    const bf16* __restrict__ tin, bf16* __restrict__ tout, int spb_shift)
{
    constexpr int T = N/16;
    constexpr int NQT = N/64;
    constexpr int VP = N + 8;
    __shared__ bf16 Ks[N][40];
    __shared__ bf16 Vs[32][VP];
    const int tid = threadIdx.x;
    const int lane = tid & 63, w = tid >> 6;
    const int ll = lane & 15, lg = lane >> 4;
    const int sh = blockIdx.x;
    const int s = sh >> 2, h = sh & 3;
    const size_t base = (size_t)sh * N * 32;

    #pragma unroll
    for (int r=0;r<N/64;r++){
        int idx = r*256 + tid;
        int n = idx >> 2, c = idx & 3;
        *(bf16x8*)&Ks[n][c*8] = *(const bf16x8*)&Kb[base + (size_t)n*32 + c*8];
    }
    #pragma unroll
    for (int r=0;r<N/64;r++){
        int idx = r*256 + tid;
        int dd = idx / (N/8), nc = idx % (N/8);
        *(bf16x8*)&Vs[dd][nc*8] = *(const bf16x8*)&Vt[base + (size_t)dd*N + nc*8];
    }
    bf16x8 qf[NQT];
    #pragma unroll
    for (int qt=0;qt<NQT;qt++)
        qf[qt] = *(const bf16x8*)&Qb[base + (size_t)(w*(N/4) + qt*16 + ll)*32 + lg*8];
    __syncthreads();

    const f32x4 Z4 = {0.f,0.f,0.f,0.f};
    f32x4 Oacc[NQT][2];
    float smv[NQT];

    #pragma unroll
    for (int qt=0; qt<NQT; ++qt){
        f32x4 sc[T];
        #pragma unroll
        for (int t=0;t<T;t++){
            bf16x8 kf = *(const bf16x8*)&Ks[t*16+ll][lg*8];
            sc[t] = mfma16(kf, qf[qt], Z4);   // D[col=q=ll][row=key=t*16+lg*4+r]
        }
        float mx = sc[0][0];
        #pragma unroll
        for (int t=0;t<T;t++)
            #pragma unroll
            for (int r=0;r<4;r++) mx = fmaxf(mx, sc[t][r]);
        mx = fmaxf(mx, __shfl_xor(mx, 16));
        mx = fmaxf(mx, __shfl_xor(mx, 32));
        float sm = 0.f;
        #pragma unroll
        for (int t=0;t<T;t++){
            #pragma unroll
            for (int r=0;r<4;r++){ float p = exp2f(sc[t][r] - mx); sc[t][r] = p; sm += p; }
        }
        sm += __shfl_xor(sm, 16);
        sm += __shfl_xor(sm, 32);
        smv[qt] = sm;

        f32x4 O0 = Z4, O1 = Z4;
        #pragma unroll
        for (int ks=0; ks<N/32; ++ks){
            bf16x4 pa = cvt4(sc[2*ks]), pb = cvt4(sc[2*ks+1]);
            bf16x8 pf;
            #pragma unroll
            for (int j=0;j<4;j++){ pf[j] = pa[j]; pf[4+j] = pb[j]; }
            bf16x4 a0 = *(const bf16x4*)&Vs[ll][ks*32 + lg*4];
            bf16x4 a1 = *(const bf16x4*)&Vs[ll][ks*32 + lg*4 + 16];
            bf16x4 b0 = *(const bf16x4*)&Vs[16+ll][ks*32 + lg*4];
            bf16x4 b1 = *(const bf16x4*)&Vs[16+ll][ks*32 + lg*4 + 16];
            bf16x8 v0, v1;
            #pragma unroll
            for (int j=0;j<4;j++){ v0[j]=a0[j]; v0[4+j]=a1[j]; v1[j]=b0[j]; v1[4+j]=b1[j]; }
            O0 = mfma16(v0, pf, O0);   // D[col=q=ll][row=dout=lg*4+r]
            O1 = mfma16(v1, pf, O1);
        }
        Oacc[qt][0] = O0; Oacc[qt][1] = O1;
    }

    __syncthreads();   // Ks/Vs dead; reuse Ks as O staging
    #pragma unroll
    for (int qt=0; qt<NQT; ++qt){
        float inv = 1.f / smv[qt];
        int q = w*(N/4) + qt*16 + ll;
        #pragma unroll
        for (int dt=0; dt<2; ++dt){
            bf16x4 o4;
            #pragma unroll
            for (int r=0;r<4;r++) o4[r] = (bf16)(Oacc[qt][dt][r]*inv);
            *(bf16x4*)&Ks[q][dt*16 + lg*4] = o4;
        }
    }
    __syncthreads();
    const int spb_mask = (1 << spb_shift) - 1;
    #pragma unroll
    for (int it=0; it<N/64; ++it){
        int q = it*64 + (tid >> 2);
        int part = tid & 3;
        size_t ti = ((size_t)(s*N + q))*128 + h*32 + part*8;
        size_t to = ((size_t)((((s >> spb_shift)*N + q) << spb_shift) + (s & spb_mask)))*128 + h*32 + part*8;
        bf16x8 a = *(const bf16x8*)&Ks[q][part*8];
        bf16x8 rs = *(const bf16x8*)&tin[ti];
        bf16x8 o;
        #pragma unroll
        for (int j=0;j<8;j++) o[j] = (bf16)((float)a[j] + (float)rs[j]);
        *(bf16x8*)&tout[to] = o;
    }
}

// ---------------------------------------------------------------------------
// K4a: proj_out GEMM, partial GroupNorm sums only (r6 verbatim).
// ---------------------------------------------------------------------------
__global__ __launch_bounds__(256) void k_gnsum(
    const bf16* __restrict__ f, const float* __restrict__ Wo, float* __restrict__ part)
{
    __shared__ bf16 As[128][136];
    __shared__ bf16 Bs[64][136];
    const int tid = threadIdx.x;
    const int lane = tid & 63, w = tid >> 6;
    const int ll = lane & 15, lg = lane >> 4;
    const int b  = blockIdx.x >> 11;
    const int ms = (blockIdx.x >> 9) & 3;
    const int ns = blockIdx.x & 511;
    const int n0 = ns*64, o0 = ms*128;

    #pragma unroll
    for (int r=0;r<16;r++){
        int idx = r*256 + tid;
        int o = idx >> 5, q = idx & 31;
        f32x4 v = *(const f32x4*)(Wo + (size_t)(o0+o)*128 + q*4);
        *(bf16x4*)&As[o][q*4] = cvt4(v);
    }
    #pragma unroll
    for (int r=0;r<4;r++){
        int idx = r*256 + tid;
        int nl = idx >> 4, ch = idx & 15;
        *(bf16x8*)&Bs[nl][ch*8] = *(const bf16x8*)&f[(size_t)(b*32768 + n0 + nl)*128 + ch*8];
    }
    __syncthreads();
    const f32x4 Z4 = {0.f,0.f,0.f,0.f};
    f32x4 acc[2][4];
    #pragma unroll
    for (int i=0;i<2;i++){ acc[i][0]=Z4; acc[i][1]=Z4; acc[i][2]=Z4; acc[i][3]=Z4; }
    #pragma unroll
    for (int ks=0;ks<4;ks++){
        bf16x8 af[2], bfr[4];
        #pragma unroll
        for (int mt=0;mt<2;mt++) af[mt]  = *(const bf16x8*)&As[w*32+mt*16+ll][ks*32+lg*8];
        #pragma unroll
        for (int nt=0;nt<4;nt++) bfr[nt] = *(const bf16x8*)&Bs[nt*16+ll][ks*32+lg*8];
        #pragma unroll
        for (int mt=0;mt<2;mt++)
            #pragma unroll
            for (int nt=0;nt<4;nt++)
                acc[mt][nt] = mfma16(af[mt], bfr[nt], acc[mt][nt]);
    }
    #pragma unroll
    for (int mt=0;mt<2;mt++){
        float ps=0.f, pss=0.f;
        #pragma unroll
        for (int nt=0;nt<4;nt++)
            #pragma unroll
            for (int r=0;r<4;r++){ float v = acc[mt][nt][r]; ps += v; pss += v*v; }
        #pragma unroll
        for (int d=1; d<64; d<<=1){ ps += __shfl_xor(ps,d); pss += __shfl_xor(pss,d); }
        if (lane == 0){
            int g = ms*8 + w*2 + mt;
            size_t pi = ((size_t)(b*32+g)*512 + ns)*2;
            part[pi] = ps; part[pi+1] = pss;
        }
    }
}

__global__ __launch_bounds__(256) void k_gnstat(
    const float* __restrict__ part, float* __restrict__ stats)
{
    const int bg = blockIdx.x;
    float s = 0.f, ss = 0.f;
    for (int i = threadIdx.x; i < 512; i += 256) {
        s  += part[((size_t)bg*512 + i)*2];
        ss += part[((size_t)bg*512 + i)*2 + 1];
    }
    #pragma unroll
    for (int d=1; d<64; d<<=1){ s += __shfl_xor(s,d); ss += __shfl_xor(ss,d); }
    __shared__ float sh[8];
    const int w = threadIdx.x >> 6;
    if ((threadIdx.x & 63) == 0) { sh[w*2] = s; sh[w*2+1] = ss; }
    __syncthreads();
    if (threadIdx.x == 0) {
        float S = sh[0]+sh[2]+sh[4]+sh[6], SS = sh[1]+sh[3]+sh[5]+sh[7];
        float mean = S * (1.f/524288.f);
        float var  = SS * (1.f/524288.f) - mean*mean;
        stats[bg*2]   = mean;
        stats[bg*2+1] = rsqrtf(var + 1e-5f);
    }
}

// ---------------------------------------------------------------------------
// K5: proj_out GEMM + GroupNorm apply + residual + fp32 store (r6 verbatim).
// ---------------------------------------------------------------------------
__global__ __launch_bounds__(256) void k_apply(
    const bf16* __restrict__ f, const float* __restrict__ Wo, const float* __restrict__ x,
    const float* __restrict__ stats, const float* __restrict__ gw, const float* __restrict__ gb,
    float* __restrict__ out)
{
    __shared__ bf16 As[128][136];   // W tile during GEMM; fp32 O tile after
    __shared__ bf16 Bs[64][136];
    const int tid = threadIdx.x;
    const int lane = tid & 63, w = tid >> 6;
    const int ll = lane & 15, lg = lane >> 4;
    const int b  = blockIdx.x >> 11;
    const int ms = (blockIdx.x >> 9) & 3;
    const int ns = blockIdx.x & 511;
    const int n0 = ns*64, o0 = ms*128;

    #pragma unroll
    for (int r=0;r<16;r++){
        int idx = r*256 + tid;
        int o = idx >> 5, q = idx & 31;
        f32x4 v = *(const f32x4*)(Wo + (size_t)(o0+o)*128 + q*4);
        *(bf16x4*)&As[o][q*4] = cvt4(v);
    }
    #pragma unroll
    for (int r=0;r<4;r++){
        int idx = r*256 + tid;
        int nl = idx >> 4, ch = idx & 15;
        *(bf16x8*)&Bs[nl][ch*8] = *(const bf16x8*)&f[(size_t)(b*32768 + n0 + nl)*128 + ch*8];
    }
    __syncthreads();
    const f32x4 Z4 = {0.f,0.f,0.f,0.f};
    f32x4 acc[2][4];
    #pragma unroll
    for (int i=0;i<2;i++){ acc[i][0]=Z4; acc[i][1]=Z4; acc[i][2]=Z4; acc[i][3]=Z4; }
    #pragma unroll
    for (int ks=0;ks<4;ks++){
        bf16x8 af[2], bfr[4];
        #pragma unroll
        for (int mt=0;mt<2;mt++) af[mt]  = *(const bf16x8*)&As[w*32+mt*16+ll][ks*32+lg*8];
        #pragma unroll
        for (int nt=0;nt<4;nt++) bfr[nt] = *(const bf16x8*)&Bs[nt*16+ll][ks*32+lg*8];
        #pragma unroll
        for (int mt=0;mt<2;mt++)
            #pragma unroll
            for (int nt=0;nt<4;nt++)
                acc[mt][nt] = mfma16(af[mt], bfr[nt], acc[mt][nt]);
    }
    __syncthreads();                    // As reads done; reuse as fp32 [128][68]
    float* Od = (float*)&As[0][0];
    #pragma unroll
    for (int mt=0;mt<2;mt++){
        int g = ms*8 + w*2 + mt;
        float mean = stats[(b*32+g)*2];
        float rstd = stats[(b*32+g)*2+1];
        #pragma unroll
        for (int r=0;r<4;r++){
            int o_l = w*32 + mt*16 + lg*4 + r;
            float sw = rstd * gw[o0 + o_l];
            float sb = gb[o0 + o_l] - mean*sw;
            #pragma unroll
            for (int nt=0;nt<4;nt++)
                Od[o_l*68 + nt*16 + ll] = acc[mt][nt][r]*sw + sb;
        }
    }
    __syncthreads();
    #pragma unroll
    for (int it=0; it<8; ++it){
        int idx = it*256 + tid;
        int o_l = idx >> 4, c4 = (idx & 15)*4;
        size_t gi = (size_t)(b*512 + o0 + o_l)*32768 + n0 + c4;
        f32x4 xv = *(const f32x4*)(x + gi);
        f32x4 ov = *(const f32x4*)(Od + o_l*68 + c4);
        f32x4 res;
        #pragma unroll
        for (int j=0;j<4;j++) res[j] = xv[j] + ov[j];
        *(f32x4*)(out + gi) = res;
    }
}

// ---------------------------------------------------------------------------
extern "C" void kernel_launch(void* const* d_in, const int* in_sizes, int n_in,
                              void* d_out, int out_size, void* d_ws, size_t ws_size,
                              hipStream_t stream)
{
    (void)in_sizes; (void)n_in; (void)out_size; (void)ws_size;
    const float* x   = (const float*)d_in[0];
    const float* wi  = (const float*)d_in[1];
    const float* tq  = (const float*)d_in[2];
    const float* tk  = (const float*)d_in[3];
    const float* tv  = (const float*)d_in[4];
    const float* tnw = (const float*)d_in[5];
    const float* tnb = (const float*)d_in[6];
    const float* fq  = (const float*)d_in[7];
    const float* fk  = (const float*)d_in[8];
    const float* fv  = (const float*)d_in[9];
    const float* fnw = (const float*)d_in[10];
    const float* fnb = (const float*)d_in[11];
    const float* wo  = (const float*)d_in[12];
    const float* gnw = (const float*)d_in[13];
    const float* gnb = (const float*)d_in[14];
    float* out = (float*)d_out;

    char* ws = (char*)d_ws;
    const size_t MB = (size_t)1 << 20;
    bf16* Z    = (bf16*)(ws);            // 32MB tokens (b,h,w), reused as f_out
    bf16* QB   = (bf16*)(ws + 32*MB);    // 32MB
    bf16* KB   = (bf16*)(ws + 64*MB);    // 32MB
    bf16* VT   = (bf16*)(ws + 96*MB);    // 32MB (transposed V)
    bf16* TOUT = (bf16*)(ws + 128*MB);   // 32MB tokens (b,w,h)
    float* PART  = (float*)(ws + 32*MB); // reuses QB (dead by then)
    float* STATS = (float*)(ws + 33*MB);

    k_proj_in<<<2048, 256, 0, stream>>>(x, wi, Z);
    k_qkv<<<2048, 256, 0, stream>>>(Z, tnw, tnb, tq, tk, tv, QB, KB, VT, 8);
    k_attn<256><<<2048, 256, 0, stream>>>(QB, KB, VT, Z, TOUT, 7);
    k_qkv<<<2048, 256, 0, stream>>>(TOUT, fnw, fnb, fq, fk, fv, QB, KB, VT, 7);
    k_attn<128><<<4096, 256, 0, stream>>>(QB, KB, VT, TOUT, Z, 8);
    k_gnsum<<<8192, 256, 0, stream>>>(Z, wo, PART);
    k_gnstat<<<128, 256, 0, stream>>>(PART, STATS);
    k_apply<<<8192, 256, 0, stream>>>(Z, wo, x, STATS, gnw, gnb, out);
}

// Round 11
// 383.701 us; speedup vs baseline: 1.1269x; 1.0373x over previous
//
#include <hip/hip_runtime.h>
#include <cstdint>

typedef __bf16 bf16;
typedef __attribute__((ext_vector_type(8))) __bf16 bf16x8;
typedef __attribute__((ext_vector_type(4))) __bf16 bf16x4;
typedef __attribute__((ext_vector_type(4))) float f32x4;

static __device__ __forceinline__ f32x4 mfma16(bf16x8 a, bf16x8 b, f32x4 c) {
    return __builtin_amdgcn_mfma_f32_16x16x32_bf16(a, b, c, 0, 0, 0);
}
static __device__ __forceinline__ bf16x4 cvt4(f32x4 v) {
    bf16x4 r; r[0]=(bf16)v[0]; r[1]=(bf16)v[1]; r[2]=(bf16)v[2]; r[3]=(bf16)v[3]; return r;
}

// ---------------------------------------------------------------------------
// K1: proj_in (r10 verbatim — Bs pitch 78, 4-way staging conflict).
// ---------------------------------------------------------------------------
__global__ __launch_bounds__(256) void k_proj_in(
    const float* __restrict__ x, const float* __restrict__ Wi, bf16* __restrict__ z)
{
    __shared__ bf16 As[128][72];
    __shared__ bf16 Bs[64][78];
    const int tid = threadIdx.x;
    const int lane = tid & 63, w = tid >> 6;
    const int ll = lane & 15, lg = lane >> 4;
    const int b = blockIdx.x >> 9;
    const int n0 = (blockIdx.x & 511) * 64;
    const float* xb = x + (size_t)b * 512 * 32768;

    f32x4 acc[2][4];
    const f32x4 Z4 = {0.f,0.f,0.f,0.f};
    #pragma unroll
    for (int i=0;i<2;i++) { acc[i][0]=Z4; acc[i][1]=Z4; acc[i][2]=Z4; acc[i][3]=Z4; }

    for (int c0 = 0; c0 < 512; c0 += 64) {
        #pragma unroll
        for (int r = 0; r < 8; ++r) {
            int idx = r*256 + tid;
            int o = idx >> 4, cq = idx & 15;
            f32x4 v = *(const f32x4*)(Wi + (size_t)o*512 + c0 + cq*4);
            *(bf16x4*)&As[o][cq*4] = cvt4(v);
        }
        #pragma unroll
        for (int r = 0; r < 4; ++r) {
            int idx = r*256 + tid;
            int k = idx >> 4, nq = idx & 15;
            f32x4 v = *(const f32x4*)(xb + (size_t)(c0 + k)*32768 + n0 + nq*4);
            #pragma unroll
            for (int j=0;j<4;j++) Bs[nq*4+j][k] = (bf16)v[j];
        }
        __syncthreads();
        #pragma unroll
        for (int ks = 0; ks < 2; ++ks) {
            bf16x8 af[2], bfr[4];
            #pragma unroll
            for (int mt=0;mt<2;mt++) af[mt]  = *(const bf16x8*)&As[w*32+mt*16+ll][ks*32+lg*8];
            #pragma unroll
            for (int nt=0;nt<4;nt++) bfr[nt] = *(const bf16x8*)&Bs[nt*16+ll][ks*32+lg*8];
            #pragma unroll
            for (int mt=0;mt<2;mt++)
                #pragma unroll
                for (int nt=0;nt<4;nt++)
                    acc[mt][nt] = mfma16(af[mt], bfr[nt], acc[mt][nt]);
        }
        __syncthreads();
    }
    #pragma unroll
    for (int mt=0;mt<2;mt++)
      #pragma unroll
      for (int nt=0;nt<4;nt++) {
        int o0 = w*32 + mt*16 + lg*4;
        int token = b*32768 + n0 + nt*16 + ll;
        *(bf16x4*)&z[(size_t)token*128 + o0] = cvt4(acc[mt][nt]);
      }
}

// ---------------------------------------------------------------------------
// K2: fused LayerNorm + QKV projection (r10 verbatim — xa hoist).
// ---------------------------------------------------------------------------
__global__ __launch_bounds__(256) void k_qkv(
    const bf16* __restrict__ zin, const float* __restrict__ lnw, const float* __restrict__ lnb,
    const float* __restrict__ Wq, const float* __restrict__ Wk, const float* __restrict__ Wv,
    bf16* __restrict__ Qb, bf16* __restrict__ Kb, bf16* __restrict__ Vt, int nshift)
{
    __shared__ bf16 xs[64][136];
    __shared__ bf16 wsm[128][136];
    const int tid = threadIdx.x;
    const int lane = tid & 63, w = tid >> 6;
    const int ll = lane & 15, lg = lane >> 4;
    const int t0 = blockIdx.x * 64;
    const int N = 1 << nshift;

    {
        const int sub = tid & 15;
        float wv[8], bv[8];
        #pragma unroll
        for (int j=0;j<8;j++){ wv[j]=lnw[sub*8+j]; bv[j]=lnb[sub*8+j]; }
        #pragma unroll
        for (int r=0;r<4;r++){
            int tl = r*16 + (tid >> 4);
            bf16x8 v = *(const bf16x8*)&zin[(size_t)(t0+tl)*128 + sub*8];
            float f[8]; float sm=0.f, ssq=0.f;
            #pragma unroll
            for (int j=0;j<8;j++){ f[j]=(float)v[j]; sm+=f[j]; ssq+=f[j]*f[j]; }
            #pragma unroll
            for (int d=1; d<16; d<<=1){ sm += __shfl_xor(sm,d); ssq += __shfl_xor(ssq,d); }
            float mean = sm*(1.f/128.f);
            float var  = ssq*(1.f/128.f) - mean*mean;
            float rr = rsqrtf(var + 1e-5f);
            bf16x8 ov;
            #pragma unroll
            for (int j=0;j<8;j++) ov[j] = (bf16)((f[j]-mean)*rr*wv[j] + bv[j]);
            *(bf16x8*)&xs[tl][sub*8] = ov;
        }
    }
    __syncthreads();   // xs ready for all waves

    // hoist x fragments once (xs is never rewritten)
    bf16x8 xa[4][4];   // [ks][tt]
    #pragma unroll
    for (int ks=0; ks<4; ++ks)
        #pragma unroll
        for (int tt=0;tt<4;tt++) xa[ks][tt] = *(const bf16x8*)&xs[tt*16+ll][ks*32+lg*8];

    const float* Wm[3] = {Wq, Wk, Wv};
    const f32x4 Z4 = {0.f,0.f,0.f,0.f};
    for (int m = 0; m < 3; ++m) {
        if (m > 0) __syncthreads();   // previous phase's wsm readers done
        const float scale = (m == 0) ? 0.25503486f : 1.0f;  // log2(e)/sqrt(32)
        #pragma unroll
        for (int r=0;r<16;r++){
            int idx = r*256 + tid;
            int o = idx >> 5, q = idx & 31;
            f32x4 v = *(const f32x4*)(Wm[m] + (size_t)o*128 + q*4);
            v[0]*=scale; v[1]*=scale; v[2]*=scale; v[3]*=scale;
            *(bf16x4*)&wsm[o][q*4] = cvt4(v);
        }
        __syncthreads();
        f32x4 acc[4][2];
        #pragma unroll
        for (int i=0;i<4;i++){ acc[i][0]=Z4; acc[i][1]=Z4; }
        #pragma unroll
        for (int ks=0; ks<4; ++ks){
            bf16x8 wb[2];
            #pragma unroll
            for (int ot=0;ot<2;ot++) wb[ot] = *(const bf16x8*)&wsm[w*32+ot*16+ll][ks*32+lg*8];
            if (m < 2) {
                #pragma unroll
                for (int tt=0;tt<4;tt++)
                    #pragma unroll
                    for (int ot=0;ot<2;ot++)
                        acc[tt][ot] = mfma16(xa[ks][tt], wb[ot], acc[tt][ot]);   // D[token][o]
            } else {
                #pragma unroll
                for (int tt=0;tt<4;tt++)
                    #pragma unroll
                    for (int ot=0;ot<2;ot++)
                        acc[tt][ot] = mfma16(wb[ot], xa[ks][tt], acc[tt][ot]);   // D[o][token]
            }
        }
        if (m < 2) {
            bf16* dst = (m==0) ? Qb : Kb;
            #pragma unroll
            for (int tt=0;tt<4;tt++)
              #pragma unroll
              for (int ot=0;ot<2;ot++)
                #pragma unroll
                for (int r=0;r<4;r++){
                    int token = t0 + tt*16 + lg*4 + r;
                    int sq = token >> nshift, n = token & (N-1);
                    int dk = ot*16 + ll;
                    dst[((size_t)(sq*4 + w)*N + n)*32 + dk] = (bf16)acc[tt][ot][r];
                }
        } else {
            #pragma unroll
            for (int tt=0;tt<4;tt++)
              #pragma unroll
              for (int ot=0;ot<2;ot++)
                #pragma unroll
                for (int r=0;r<4;r++){
                    int dk = ot*16 + lg*4 + r;
                    int token = t0 + tt*16 + ll;
                    int sq = token >> nshift, n = token & (N-1);
                    Vt[((size_t)(sq*4 + w)*32 + dk)*N + n] = (bf16)acc[tt][ot][r];
                }
        }
    }
}

// ---------------------------------------------------------------------------
// K3: attention (r6/r10 verbatim — verified).
// ---------------------------------------------------------------------------
template<int N>
__global__ __launch_bounds__(256, 2) void k_attn(
    const bf16* __restrict__ Qb, const bf16* __restrict__ Kb, const bf16* __restrict__ Vt,
    const bf16* __restrict__ tin, bf16* __restrict__ tout, int spb_shift)
{
    constexpr int T = N/16;
    constexpr int NQT = N/64;
    constexpr int VP = N + 8;
    __shared__ bf16 Ks[N][40];
    __shared__ bf16 Vs[32][VP];
    const int tid = threadIdx.x;
    const int lane = tid & 63, w = tid >> 6;
    const int ll = lane & 15, lg = lane >> 4;
    const int sh = blockIdx.x;
    const int s = sh >> 2, h = sh & 3;
    const size_t base = (size_t)sh * N * 32;

    #pragma unroll
    for (int r=0;r<N/64;r++){
        int idx = r*256 + tid;
        int n = idx >> 2, c = idx & 3;
        *(bf16x8*)&Ks[n][c*8] = *(const bf16x8*)&Kb[base + (size_t)n*32 + c*8];
    }
    #pragma unroll
    for (int r=0;r<N/64;r++){
        int idx = r*256 + tid;
        int dd = idx / (N/8), nc = idx % (N/8);
        *(bf16x8*)&Vs[dd][nc*8] = *(const bf16x8*)&Vt[base + (size_t)dd*N + nc*8];
    }
    bf16x8 qf[NQT];
    #pragma unroll
    for (int qt=0;qt<NQT;qt++)
        qf[qt] = *(const bf16x8*)&Qb[base + (size_t)(w*(N/4) + qt*16 + ll)*32 + lg*8];
    __syncthreads();

    const f32x4 Z4 = {0.f,0.f,0.f,0.f};
    f32x4 Oacc[NQT][2];
    float smv[NQT];

    #pragma unroll
    for (int qt=0; qt<NQT; ++qt){
        f32x4 sc[T];
        #pragma unroll
        for (int t=0;t<T;t++){
            bf16x8 kf = *(const bf16x8*)&Ks[t*16+ll][lg*8];
            sc[t] = mfma16(kf, qf[qt], Z4);   // D[col=q=ll][row=key=t*16+lg*4+r]
        }
        float mx = sc[0][0];
        #pragma unroll
        for (int t=0;t<T;t++)
            #pragma unroll
            for (int r=0;r<4;r++) mx = fmaxf(mx, sc[t][r]);
        mx = fmaxf(mx, __shfl_xor(mx, 16));
        mx = fmaxf(mx, __shfl_xor(mx, 32));
        float sm = 0.f;
        #pragma unroll
        for (int t=0;t<T;t++){
            #pragma unroll
            for (int r=0;r<4;r++){ float p = exp2f(sc[t][r] - mx); sc[t][r] = p; sm += p; }
        }
        sm += __shfl_xor(sm, 16);
        sm += __shfl_xor(sm, 32);
        smv[qt] = sm;

        f32x4 O0 = Z4, O1 = Z4;
        #pragma unroll
        for (int ks=0; ks<N/32; ++ks){
            bf16x4 pa = cvt4(sc[2*ks]), pb = cvt4(sc[2*ks+1]);
            bf16x8 pf;
            #pragma unroll
            for (int j=0;j<4;j++){ pf[j] = pa[j]; pf[4+j] = pb[j]; }
            bf16x4 a0 = *(const bf16x4*)&Vs[ll][ks*32 + lg*4];
            bf16x4 a1 = *(const bf16x4*)&Vs[ll][ks*32 + lg*4 + 16];
            bf16x4 b0 = *(const bf16x4*)&Vs[16+ll][ks*32 + lg*4];
            bf16x4 b1 = *(const bf16x4*)&Vs[16+ll][ks*32 + lg*4 + 16];
            bf16x8 v0, v1;
            #pragma unroll
            for (int j=0;j<4;j++){ v0[j]=a0[j]; v0[4+j]=a1[j]; v1[j]=b0[j]; v1[4+j]=b1[j]; }
            O0 = mfma16(v0, pf, O0);   // D[col=q=ll][row=dout=lg*4+r]
            O1 = mfma16(v1, pf, O1);
        }
        Oacc[qt][0] = O0; Oacc[qt][1] = O1;
    }

    __syncthreads();   // Ks/Vs dead; reuse Ks as O staging
    #pragma unroll
    for (int qt=0; qt<NQT; ++qt){
        float inv = 1.f / smv[qt];
        int q = w*(N/4) + qt*16 + ll;
        #pragma unroll
        for (int dt=0; dt<2; ++dt){
            bf16x4 o4;
            #pragma unroll
            for (int r=0;r<4;r++) o4[r] = (bf16)(Oacc[qt][dt][r]*inv);
            *(bf16x4*)&Ks[q][dt*16 + lg*4] = o4;
        }
    }
    __syncthreads();
    const int spb_mask = (1 << spb_shift) - 1;
    #pragma unroll
    for (int it=0; it<N/64; ++it){
        int q = it*64 + (tid >> 2);
        int part = tid & 3;
        size_t ti = ((size_t)(s*N + q))*128 + h*32 + part*8;
        size_t to = ((size_t)((((s >> spb_shift)*N + q) << spb_shift) + (s & spb_mask)))*128 + h*32 + part*8;
        bf16x8 a = *(const bf16x8*)&Ks[q][part*8];
        bf16x8 rs = *(const bf16x8*)&tin[ti];
        bf16x8 o;
        #pragma unroll
        for (int j=0;j<8;j++) o[j] = (bf16)((float)a[j] + (float)rs[j]);
        *(bf16x8*)&tout[to] = o;
    }
}

// ---------------------------------------------------------------------------
// K4a: proj_out GEMM, partial GroupNorm sums. NEW: 4 sub-slices (256 tokens)
// per block, Wo staged ONCE (was once per 64 tokens -> 4x W-staging saved);
// sum/sumsq accumulated in registers across slices, single reduction+write.
// ---------------------------------------------------------------------------
__global__ __launch_bounds__(256) void k_gnsum(
    const bf16* __restrict__ f, const float* __restrict__ Wo, float* __restrict__ part)
{
    __shared__ bf16 As[128][136];
    __shared__ bf16 Bs[64][136];
    const int tid = threadIdx.x;
    const int lane = tid & 63, w = tid >> 6;
    const int ll = lane & 15, lg = lane >> 4;
    const int b   = blockIdx.x >> 9;         // 4
    const int ms  = (blockIdx.x >> 7) & 3;   // 4
    const int ns4 = blockIdx.x & 127;        // 128 slices of 256 tokens
    const int o0 = ms*128;

    #pragma unroll
    for (int r=0;r<16;r++){
        int idx = r*256 + tid;
        int o = idx >> 5, q = idx & 31;
        f32x4 v = *(const f32x4*)(Wo + (size_t)(o0+o)*128 + q*4);
        *(bf16x4*)&As[o][q*4] = cvt4(v);
    }

    const f32x4 Z4 = {0.f,0.f,0.f,0.f};
    float ps[2] = {0.f, 0.f}, pss[2] = {0.f, 0.f};

    for (int sub = 0; sub < 4; ++sub){
        if (sub > 0) __syncthreads();        // prior slice's Bs readers done
        const int n0 = ns4*256 + sub*64;
        #pragma unroll
        for (int r=0;r<4;r++){
            int idx = r*256 + tid;
            int nl = idx >> 4, ch = idx & 15;
            *(bf16x8*)&Bs[nl][ch*8] = *(const bf16x8*)&f[(size_t)(b*32768 + n0 + nl)*128 + ch*8];
        }
        __syncthreads();                     // As (first iter) + Bs visible
        f32x4 acc[2][4];
        #pragma unroll
        for (int i=0;i<2;i++){ acc[i][0]=Z4; acc[i][1]=Z4; acc[i][2]=Z4; acc[i][3]=Z4; }
        #pragma unroll
        for (int ks=0;ks<4;ks++){
            bf16x8 af[2], bfr[4];
            #pragma unroll
            for (int mt=0;mt<2;mt++) af[mt]  = *(const bf16x8*)&As[w*32+mt*16+ll][ks*32+lg*8];
            #pragma unroll
            for (int nt=0;nt<4;nt++) bfr[nt] = *(const bf16x8*)&Bs[nt*16+ll][ks*32+lg*8];
            #pragma unroll
            for (int mt=0;mt<2;mt++)
                #pragma unroll
                for (int nt=0;nt<4;nt++)
                    acc[mt][nt] = mfma16(af[mt], bfr[nt], acc[mt][nt]);
        }
        #pragma unroll
        for (int mt=0;mt<2;mt++)
            #pragma unroll
            for (int nt=0;nt<4;nt++)
                #pragma unroll
                for (int r=0;r<4;r++){
                    float v = acc[mt][nt][r];
                    ps[mt] += v; pss[mt] += v*v;
                }
    }
    #pragma unroll
    for (int mt=0;mt<2;mt++){
        float p = ps[mt], q = pss[mt];
        #pragma unroll
        for (int d=1; d<64; d<<=1){ p += __shfl_xor(p,d); q += __shfl_xor(q,d); }
        if (lane == 0){
            int g = ms*8 + w*2 + mt;
            size_t pi = ((size_t)(b*32+g)*128 + ns4)*2;
            part[pi] = p; part[pi+1] = q;
        }
    }
}

__global__ __launch_bounds__(256) void k_gnstat(
    const float* __restrict__ part, float* __restrict__ stats)
{
    const int bg = blockIdx.x;
    float s = 0.f, ss = 0.f;
    if (threadIdx.x < 128) {
        s  = part[((size_t)bg*128 + threadIdx.x)*2];
        ss = part[((size_t)bg*128 + threadIdx.x)*2 + 1];
    }
    #pragma unroll
    for (int d=1; d<64; d<<=1){ s += __shfl_xor(s,d); ss += __shfl_xor(ss,d); }
    __shared__ float sh[8];
    const int w = threadIdx.x >> 6;
    if ((threadIdx.x & 63) == 0) { sh[w*2] = s; sh[w*2+1] = ss; }
    __syncthreads();
    if (threadIdx.x == 0) {
        float S = sh[0]+sh[2], SS = sh[1]+sh[3];
        float mean = S * (1.f/524288.f);
        float var  = SS * (1.f/524288.f) - mean*mean;
        stats[bg*2]   = mean;
        stats[bg*2+1] = rsqrtf(var + 1e-5f);
    }
}

// ---------------------------------------------------------------------------
// K5: proj_out GEMM + GroupNorm apply + residual + fp32 store (r10 verbatim).
// ---------------------------------------------------------------------------
__global__ __launch_bounds__(256) void k_apply(
    const bf16* __restrict__ f, const float* __restrict__ Wo, const float* __restrict__ x,
    const float* __restrict__ stats, const float* __restrict__ gw, const float* __restrict__ gb,
    float* __restrict__ out)
{
    __shared__ bf16 As[128][136];   // W tile during GEMM; fp32 O tile after
    __shared__ bf16 Bs[64][136];
    const int tid = threadIdx.x;
    const int lane = tid & 63, w = tid >> 6;
    const int ll = lane & 15, lg = lane >> 4;
    const int b  = blockIdx.x >> 11;
    const int ms = (blockIdx.x >> 9) & 3;
    const int ns = blockIdx.x & 511;
    const int n0 = ns*64, o0 = ms*128;

    #pragma unroll
    for (int r=0;r<16;r++){
        int idx = r*256 + tid;
        int o = idx >> 5, q = idx & 31;
        f32x4 v = *(const f32x4*)(Wo + (size_t)(o0+o)*128 + q*4);
        *(bf16x4*)&As[o][q*4] = cvt4(v);
    }
    #pragma unroll
    for (int r=0;r<4;r++){
        int idx = r*256 + tid;
        int nl = idx >> 4, ch = idx & 15;
        *(bf16x8*)&Bs[nl][ch*8] = *(const bf16x8*)&f[(size_t)(b*32768 + n0 + nl)*128 + ch*8];
    }
    __syncthreads();
    const f32x4 Z4 = {0.f,0.f,0.f,0.f};
    f32x4 acc[2][4];
    #pragma unroll
    for (int i=0;i<2;i++){ acc[i][0]=Z4; acc[i][1]=Z4; acc[i][2]=Z4; acc[i][3]=Z4; }
    #pragma unroll
    for (int ks=0;ks<4;ks++){
        bf16x8 af[2], bfr[4];
        #pragma unroll
        for (int mt=0;mt<2;mt++) af[mt]  = *(const bf16x8*)&As[w*32+mt*16+ll][ks*32+lg*8];
        #pragma unroll
        for (int nt=0;nt<4;nt++) bfr[nt] = *(const bf16x8*)&Bs[nt*16+ll][ks*32+lg*8];
        #pragma unroll
        for (int mt=0;mt<2;mt++)
            #pragma unroll
            for (int nt=0;nt<4;nt++)
                acc[mt][nt] = mfma16(af[mt], bfr[nt], acc[mt][nt]);
    }
    __syncthreads();                    // As reads done; reuse as fp32 [128][68]
    float* Od = (float*)&As[0][0];
    #pragma unroll
    for (int mt=0;mt<2;mt++){
        int g = ms*8 + w*2 + mt;
        float mean = stats[(b*32+g)*2];
        float rstd = stats[(b*32+g)*2+1];
        #pragma unroll
        for (int r=0;r<4;r++){
            int o_l = w*32 + mt*16 + lg*4 + r;
            float sw = rstd * gw[o0 + o_l];
            float sb = gb[o0 + o_l] - mean*sw;
            #pragma unroll
            for (int nt=0;nt<4;nt++)
                Od[o_l*68 + nt*16 + ll] = acc[mt][nt][r]*sw + sb;
        }
    }
    __syncthreads();
    #pragma unroll
    for (int it=0; it<8; ++it){
        int idx = it*256 + tid;
        int o_l = idx >> 4, c4 = (idx & 15)*4;
        size_t gi = (size_t)(b*512 + o0 + o_l)*32768 + n0 + c4;
        f32x4 xv = *(const f32x4*)(x + gi);
        f32x4 ov = *(const f32x4*)(Od + o_l*68 + c4);
        f32x4 res;
        #pragma unroll
        for (int j=0;j<4;j++) res[j] = xv[j] + ov[j];
        *(f32x4*)(out + gi) = res;
    }
}

// ---------------------------------------------------------------------------
extern "C" void kernel_launch(void* const* d_in, const int* in_sizes, int n_in,
                              void* d_out, int out_size, void* d_ws, size_t ws_size,
                              hipStream_t stream)
{
    (void)in_sizes; (void)n_in; (void)out_size; (void)ws_size;
    const float* x   = (const float*)d_in[0];
    const float* wi  = (const float*)d_in[1];
    const float* tq  = (const float*)d_in[2];
    const float* tk  = (const float*)d_in[3];
    const float* tv  = (const float*)d_in[4];
    const float* tnw = (const float*)d_in[5];
    const float* tnb = (const float*)d_in[6];
    const float* fq  = (const float*)d_in[7];
    const float* fk  = (const float*)d_in[8];
    const float* fv  = (const float*)d_in[9];
    const float* fnw = (const float*)d_in[10];
    const float* fnb = (const float*)d_in[11];
    const float* wo  = (const float*)d_in[12];
    const float* gnw = (const float*)d_in[13];
    const float* gnb = (const float*)d_in[14];
    float* out = (float*)d_out;

    char* ws = (char*)d_ws;
    const size_t MB = (size_t)1 << 20;
    bf16* Z    = (bf16*)(ws);            // 32MB tokens (b,h,w), reused as f_out
    bf16* QB   = (bf16*)(ws + 32*MB);    // 32MB
    bf16* KB   = (bf16*)(ws + 64*MB);    // 32MB
    bf16* VT   = (bf16*)(ws + 96*MB);    // 32MB (transposed V)
    bf16* TOUT = (bf16*)(ws + 128*MB);   // 32MB tokens (b,w,h)
    float* PART  = (float*)(ws + 32*MB); // reuses QB (dead by then), 128KB
    float* STATS = (float*)(ws + 33*MB);

    k_proj_in<<<2048, 256, 0, stream>>>(x, wi, Z);
    k_qkv<<<2048, 256, 0, stream>>>(Z, tnw, tnb, tq, tk, tv, QB, KB, VT, 8);
    k_attn<256><<<2048, 256, 0, stream>>>(QB, KB, VT, Z, TOUT, 7);
    k_qkv<<<2048, 256, 0, stream>>>(TOUT, fnw, fnb, fq, fk, fv, QB, KB, VT, 7);
    k_attn<128><<<4096, 256, 0, stream>>>(QB, KB, VT, TOUT, Z, 8);
    k_gnsum<<<2048, 256, 0, stream>>>(Z, wo, PART);
    k_gnstat<<<128, 256, 0, stream>>>(PART, STATS);
    k_apply<<<8192, 256, 0, stream>>>(Z, wo, x, STATS, gnw, gnb, out);
}